// Round 7
// baseline (331.401 us; speedup 1.0000x reference)
//
#include <hip/hip_runtime.h>

#define INV_STD 0.9999950000374997f

typedef unsigned short u16;
typedef __bf16 bf16x8 __attribute__((ext_vector_type(8)));
typedef __bf16 bf16x4 __attribute__((ext_vector_type(4)));
typedef float f32x4 __attribute__((ext_vector_type(4)));

__device__ __forceinline__ u16 f2bf(float f) {
    unsigned int u = __float_as_uint(f);
    u += 0x7fffu + ((u >> 16) & 1u);   // RNE
    return (u16)(u >> 16);
}

// async global->LDS, 16B per lane. LDS dest must be wave-uniform base (HW adds lane*16).
__device__ __forceinline__ void gl_lds16(const void* g, void* l) {
    __builtin_amdgcn_global_load_lds(
        (const __attribute__((address_space(1))) unsigned int*)(unsigned long long)g,
        (__attribute__((address_space(3))) unsigned int*)(unsigned int)(unsigned long long)l,
        16, 0, 0);
}

__device__ __forceinline__ f32x4 mfma16(bf16x8 a, bf16x8 b, f32x4 c) {
    return __builtin_amdgcn_mfma_f32_16x16x32_bf16(a, b, c, 0, 0, 0);
}

__device__ __forceinline__ unsigned lds_off(const void* p) {
    return (unsigned)(unsigned long long)p;
}

// hardware transpose read: lane reads 4 bf16 at byte addr +0,+32,+64,+96
__device__ __forceinline__ bf16x4 tr_read(unsigned addr) {
    bf16x4 r;
    asm volatile("ds_read_b64_tr_b16 %0, %1" : "=v"(r) : "v"(addr));
    return r;
}

__device__ __forceinline__ bf16x8 ldg8(const u16* p) {
    return *(const bf16x8*)p;
}

// ---------------- all weight prep in one launch ----------------
__global__ void wprep(const float* __restrict__ wq1, const float* __restrict__ gq1,
                      const float* __restrict__ wq2, const float* __restrict__ gq2,
                      const float* __restrict__ wo,  const float* __restrict__ go,
                      u16* __restrict__ WQ1B, u16* __restrict__ WQ2B, u16* __restrict__ WOB) {
    int blk = blockIdx.x;
    int t = threadIdx.x;
    if (blk < 512) {
        long i = (long)blk * 256 + t;
        int o = (int)(i >> 9);
        int q = (int)(i & 511);
        int r = q & 31;
        int src = (q & ~31) + ((r >> 3) & 3) * 4 + (r & 3) + ((r >> 2) & 1) * 16;
        WQ1B[i] = f2bf(wq1[(long)o * 512 + src] * (INV_STD * gq1[o]));
    } else if (blk < 768) {
        long i = (long)(blk - 512) * 256 + t;
        int o = (int)(i >> 8);
        WQ2B[i] = f2bf(wq2[i] * (INV_STD * gq2[o]));
    } else {
        long i = (long)(blk - 768) * 256 + t;
        int o = (int)(i >> 8);
        WOB[i] = f2bf(wo[i] * (INV_STD * go[o]));
    }
}

// ---------------- k/v path (tiny): one block per (b,p); p in [0,32) with zero-padding ----------------
__global__ __launch_bounds__(256) void kv_kernel(
    const float* __restrict__ proxy,                       // (B,512,19)
    const float* __restrict__ wk1, const float* __restrict__ gk1, const float* __restrict__ bk1,
    const float* __restrict__ wk2, const float* __restrict__ gk2, const float* __restrict__ bk2,
    const float* __restrict__ wv,  const float* __restrict__ gv,  const float* __restrict__ bv,
    u16* __restrict__ KB,                                  // (B,32,256) bf16, rows 19..31 zero
    u16* __restrict__ VB)                                  // (B,256,32) bf16, cols 19..31 zero
{
    int b = blockIdx.x >> 5, p = blockIdx.x & 31;
    int t = threadIdx.x;
    if (p >= 19) {
        KB[((long)b * 32 + p) * 256 + t] = 0;
        VB[((long)b * 256 + t) * 32 + p] = 0;
        return;
    }
    __shared__ float px[512];
    __shared__ float k1[256];
    for (int i = t; i < 512; i += 256) px[i] = proxy[((long)b * 512 + i) * 19 + p];
    __syncthreads();
    float aK = 0.f, aV = 0.f;
    const float4* wk1r = (const float4*)(wk1 + (long)t * 512);
    const float4* wvr  = (const float4*)(wv  + (long)t * 512);
    const float4* pxv  = (const float4*)px;
    #pragma unroll 4
    for (int c = 0; c < 128; ++c) {
        float4 pv = pxv[c];
        float4 k4 = wk1r[c];
        float4 v4 = wvr[c];
        aK += k4.x * pv.x + k4.y * pv.y + k4.z * pv.z + k4.w * pv.w;
        aV += v4.x * pv.x + v4.y * pv.y + v4.z * pv.z + v4.w * pv.w;
    }
    float k1v = fmaxf(aK * (INV_STD * gk1[t]) + bk1[t], 0.f);
    float vv  = fmaxf(aV * (INV_STD * gv[t])  + bv[t],  0.f);
    k1[t] = k1v;
    VB[((long)b * 256 + t) * 32 + p] = f2bf(vv);
    __syncthreads();
    float a2 = 0.f;
    const float4* wk2r = (const float4*)(wk2 + (long)t * 256);
    const float4* k1v4 = (const float4*)k1;
    #pragma unroll 4
    for (int c = 0; c < 64; ++c) {
        float4 w4 = wk2r[c];
        float4 kk = k1v4[c];
        a2 += w4.x * kk.x + w4.y * kk.y + w4.z * kk.z + w4.w * kk.w;
    }
    KB[((long)b * 32 + p) * 256 + t] = f2bf(fmaxf(a2 * (INV_STD * gk2[t]) + bk2[t], 0.f));
}

// ---------------- fused GEMM1: reads x (channel-major f32) directly, W1 direct from L2 ----------------
// xs double-buffered: one barrier per K-tile.
__global__ __launch_bounds__(256) void gemm1_x(
    const float* __restrict__ X,     // (B,512,16384)
    const u16* __restrict__ W,       // (256,512) bf16, K-permuted
    const float* __restrict__ bias,
    u16* __restrict__ out)           // (B*HW,256)
{
    __shared__ __align__(16) u16 xs[2][64 * 64];   // 2 x 8 KB, subtiled
    int t = threadIdx.x, lane = t & 63, w = t >> 6;
    int l16 = lane & 15, hi = lane >> 4;
    long m0 = (long)blockIdx.x * 64;
    int b = (int)(m0 >> 14);
    int pixg = (int)(m0 & 16383);
    const float* xb = X + (long)b * 512 * 16384 + pixg;
    int ca = t >> 4;       // channel within 16-group
    int aa = t & 15;       // pixel quad
    unsigned trb = lds_off(&xs[0][hi * 64 + l16]);
    f32x4 acc[4][4] = {};
    float4 xr0, xr1, xr2, xr3;
    {
        const float* p0 = xb + (long)ca * 16384 + aa * 4;
        xr0 = *(const float4*)(p0);
        xr1 = *(const float4*)(p0 + 16L * 16384);
        xr2 = *(const float4*)(p0 + 32L * 16384);
        xr3 = *(const float4*)(p0 + 48L * 16384);
    }
    #define STW(XR, P, NB) { \
        int c = (P) * 16 + ca; \
        ushort4 u; u.x = f2bf(XR.x); u.y = f2bf(XR.y); u.z = f2bf(XR.z); u.w = f2bf(XR.w); \
        *(ushort4*)&xs[NB][((aa >> 2) * 16 + (c >> 2)) * 64 + (c & 3) * 16 + (aa & 3) * 4] = u; }
    STW(xr0, 0, 0) STW(xr1, 1, 0) STW(xr2, 2, 0) STW(xr3, 3, 0)
    __syncthreads();
    for (int kt = 0; kt < 8; ++kt) {
        int k0 = kt << 6;
        if (kt < 7) {                            // prefetch next K-tile into regs (HBM)
            const float* p0 = xb + (long)(k0 + 64 + ca) * 16384 + aa * 4;
            xr0 = *(const float4*)(p0);
            xr1 = *(const float4*)(p0 + 16L * 16384);
            xr2 = *(const float4*)(p0 + 32L * 16384);
            xr3 = *(const float4*)(p0 + 48L * 16384);
        }
        unsigned tb = trb + (kt & 1) * 8192;
        #pragma unroll
        for (int kk = 0; kk < 2; ++kk) {
            bf16x8 bb[4];
            #pragma unroll
            for (int j = 0; j < 4; ++j)
                bb[j] = ldg8(W + (long)(w * 64 + j * 16 + l16) * 512 + k0 + kk * 32 + hi * 8);
            bf16x4 lo[4], hh[4];
            #pragma unroll
            for (int i = 0; i < 4; ++i) {
                unsigned a0 = tb + i * 2048 + kk * 1024;
                lo[i] = tr_read(a0);
                hh[i] = tr_read(a0 + 512);
            }
            asm volatile("s_waitcnt lgkmcnt(0)" ::: "memory");
            __builtin_amdgcn_sched_barrier(0);
            #pragma unroll
            for (int i = 0; i < 4; ++i) {
                bf16x8 a = __builtin_shufflevector(lo[i], hh[i], 0, 1, 2, 3, 4, 5, 6, 7);
                #pragma unroll
                for (int j = 0; j < 4; ++j)
                    acc[i][j] = mfma16(a, bb[j], acc[i][j]);
            }
        }
        if (kt < 7) {                            // write next tile into other buffer
            int nb = (kt + 1) & 1;
            STW(xr0, 0, nb) STW(xr1, 1, nb) STW(xr2, 2, nb) STW(xr3, 3, nb)
        }
        __syncthreads();
    }
    #undef STW
    float bj[4];
    #pragma unroll
    for (int j = 0; j < 4; ++j) bj[j] = bias[w * 64 + j * 16 + l16];
    #pragma unroll
    for (int i = 0; i < 4; ++i) {
        #pragma unroll
        for (int r = 0; r < 4; ++r) {
            long pix = m0 + i * 16 + hi * 4 + r;
            u16* orow = out + pix * 256;
            #pragma unroll
            for (int j = 0; j < 4; ++j) {
                float v = acc[i][j][r] + bj[j];
                orow[w * 64 + j * 16 + l16] = f2bf(fmaxf(v, 0.f));
            }
        }
    }
}

// ---------------- fused GEMM2 + attention + output projection ----------------
// Per-wave private k-major weight slices (no cross-wave barriers in GEMM loops),
// A direct-to-reg prefetch, operand-swapped phase 4 with float4 stores. 3 barriers total.
__global__ __launch_bounds__(256, 2) void gemm2_attn_out(
    const u16* __restrict__ A,      // Q1 (B*HW, 256) bf16
    const u16* __restrict__ W,      // W2 (256,256) bf16 (BN-folded)
    const float* __restrict__ bias, // bq2
    const u16* __restrict__ KB,     // (B,32,256) bf16
    const u16* __restrict__ VB,     // (B,256,32) bf16
    const u16* __restrict__ Wo,     // (512,256) bf16 (BN-folded)
    const float* __restrict__ obias,// bo
    float* __restrict__ out)        // (B,512,16384) fp32
{
    __shared__ __align__(16) u16 lB[2][256 * 32];  // 2 x 16 KB, per-wave 64-row k-major slices
    __shared__ __align__(16) u16 q2s[64 * 264];    // 33 KB; q2 tile, later reused as ctx tile
    __shared__ __align__(16) u16 atts[64 * 40];    //  5 KB
    int t = threadIdx.x, lane = t & 63, w = t >> 6;
    int l16 = lane & 15, hi = lane >> 4;
    long m0 = (long)blockIdx.x * 64;
    int b = (int)(m0 >> 14);
    int pixg = (int)(m0 & 16383);
    // k-major DMA source mapping: lane L fetches row (L&15), k-plane (L>>4) of its slice.
    int rW = lane & 15;
    int kW = (lane >> 4) << 3;     // u16 offset
    // ---- phase 1: GEMM2, q2 = relu(q1 · W2^T + b). Per-wave dbuf, vmcnt-synced, no barriers ----
    {
        f32x4 acc[4][4] = {};
        #pragma unroll
        for (int j = 0; j < 4; ++j)
            gl_lds16(W + (long)(w * 64 + j * 16 + rW) * 256 + kW, &lB[0][(w * 4 + j) * 512]);
        bf16x8 aC[4];
        #pragma unroll
        for (int i = 0; i < 4; ++i)
            aC[i] = ldg8(A + (m0 + i * 16 + l16) * 256 + hi * 8);
        asm volatile("s_waitcnt vmcnt(0)" ::: "memory");
        #pragma unroll
        for (int c = 0; c < 8; ++c) {
            int cur = c & 1;
            bf16x8 aN[4];
            if (c < 7) {                      // stage next chunk (other buffer) + next A frags
                int k1 = (c + 1) << 5;
                #pragma unroll
                for (int j = 0; j < 4; ++j)
                    gl_lds16(W + (long)(w * 64 + j * 16 + rW) * 256 + k1 + kW, &lB[cur ^ 1][(w * 4 + j) * 512]);
                #pragma unroll
                for (int i = 0; i < 4; ++i)
                    aN[i] = ldg8(A + (m0 + i * 16 + l16) * 256 + k1 + hi * 8);
            }
            bf16x8 bb[4];
            #pragma unroll
            for (int j = 0; j < 4; ++j)
                bb[j] = *(const bf16x8*)&lB[cur][(w * 4 + j) * 512 + hi * 128 + l16 * 8];
            #pragma unroll
            for (int i = 0; i < 4; ++i)
                #pragma unroll
                for (int j = 0; j < 4; ++j)
                    acc[i][j] = mfma16(aC[i], bb[j], acc[i][j]);
            asm volatile("s_waitcnt vmcnt(0)" ::: "memory");   // next DMA + aN arrived
            if (c < 7) {
                #pragma unroll
                for (int i = 0; i < 4; ++i) aC[i] = aN[i];
            }
        }
        float bj[4];
        #pragma unroll
        for (int j = 0; j < 4; ++j) bj[j] = bias[w * 64 + j * 16 + l16];
        #pragma unroll
        for (int i = 0; i < 4; ++i)
            #pragma unroll
            for (int r = 0; r < 4; ++r) {
                int pix = i * 16 + hi * 4 + r;
                #pragma unroll
                for (int j = 0; j < 4; ++j) {
                    float v = acc[i][j][r] + bj[j];
                    q2s[pix * 264 + w * 64 + j * 16 + l16] = f2bf(fmaxf(v, 0.f));
                }
            }
    }
    __syncthreads();
    // ---- phase 2: sim = q2 · KB^T, softmax -> atts (bf16) ----
    {
        f32x4 s0 = {}, s1 = {};
        #pragma unroll
        for (int ks = 0; ks < 8; ++ks) {
            bf16x8 a = *(const bf16x8*)&q2s[(w * 16 + l16) * 264 + ks * 32 + hi * 8];
            bf16x8 b0 = ldg8(KB + ((long)b * 32 + l16) * 256 + ks * 32 + hi * 8);
            bf16x8 b1 = ldg8(KB + ((long)b * 32 + 16 + l16) * 256 + ks * 32 + hi * 8);
            s0 = mfma16(a, b0, s0);
            s1 = mfma16(a, b1, s1);
        }
        const float scale = 0.0625f;
        #pragma unroll
        for (int r = 0; r < 4; ++r) {
            float v0 = s0[r] * scale;
            float v1 = s1[r] * scale;
            float mx = fmaxf(v0, v1);
            mx = fmaxf(mx, __shfl_xor(mx, 1));
            mx = fmaxf(mx, __shfl_xor(mx, 2));
            mx = fmaxf(mx, __shfl_xor(mx, 4));
            mx = fmaxf(mx, __shfl_xor(mx, 8));
            float e0 = __expf(v0 - mx);
            float e1 = (l16 < 3) ? __expf(v1 - mx) : 0.f;
            float s = e0 + e1;
            s += __shfl_xor(s, 1);
            s += __shfl_xor(s, 2);
            s += __shfl_xor(s, 4);
            s += __shfl_xor(s, 8);
            float inv = 1.f / s;
            int pix = w * 16 + hi * 4 + r;
            atts[pix * 40 + l16] = f2bf(e0 * inv);
            atts[pix * 40 + 16 + l16] = (l16 < 3) ? f2bf(e1 * inv) : (u16)0;
        }
    }
    __syncthreads();     // all sim reads of q2s complete; q2s reusable as ctx
    // ---- phase 3: ctx = att · VB^T -> ctxs (= q2s buffer) ----
    {
        f32x4 c4[4][4] = {};
        bf16x8 av[4], bv[4];
        #pragma unroll
        for (int mf = 0; mf < 4; ++mf)
            av[mf] = *(const bf16x8*)&atts[(mf * 16 + l16) * 40 + hi * 8];
        #pragma unroll
        for (int nf = 0; nf < 4; ++nf)
            bv[nf] = ldg8(VB + ((long)b * 256 + w * 64 + nf * 16 + l16) * 32 + hi * 8);
        #pragma unroll
        for (int mf = 0; mf < 4; ++mf)
            #pragma unroll
            for (int nf = 0; nf < 4; ++nf)
                c4[mf][nf] = mfma16(av[mf], bv[nf], c4[mf][nf]);
        #pragma unroll
        for (int mf = 0; mf < 4; ++mf)
            #pragma unroll
            for (int r = 0; r < 4; ++r) {
                int pix = mf * 16 + hi * 4 + r;
                #pragma unroll
                for (int nf = 0; nf < 4; ++nf)
                    q2s[pix * 264 + w * 64 + nf * 16 + l16] = f2bf(c4[mf][nf][r]);
            }
    }
    __syncthreads();     // ctx visible to all waves (drains all vmem too)
    // ---- phase 4: out = relu(Wo · ctx^T + bo). Operand-swapped (ctx=A, Wo=B) -> float4 stores.
    //      Per-wave dbuf Wo slices, vmcnt-synced, no barriers. 16 chunks (2 halves x 8). ----
    {
        #pragma unroll
        for (int j = 0; j < 4; ++j)
            gl_lds16(Wo + (long)(w * 64 + j * 16 + rW) * 256 + kW, &lB[0][(w * 4 + j) * 512]);
        asm volatile("s_waitcnt vmcnt(0)" ::: "memory");
        f32x4 acc2[4][4] = {};
        #pragma unroll
        for (int cc = 0; cc < 16; ++cc) {
            int cur = cc & 1;
            if (cc < 15) {                    // stage next Wo chunk into other buffer
                int nc = cc + 1;
                #pragma unroll
                for (int j = 0; j < 4; ++j)
                    gl_lds16(Wo + (long)((nc >> 3) * 256 + w * 64 + j * 16 + rW) * 256 + ((nc & 7) << 5) + kW,
                             &lB[cur ^ 1][(w * 4 + j) * 512]);
            }
            int k0 = (cc & 7) << 5;
            bf16x8 a[4], bb[4];
            #pragma unroll
            for (int m = 0; m < 4; ++m)       // ctx: A-operand (pixels = M)
                a[m] = *(const bf16x8*)&q2s[(m * 16 + l16) * 264 + k0 + hi * 8];
            #pragma unroll
            for (int n = 0; n < 4; ++n)       // Wo: B-operand (channels = N)
                bb[n] = *(const bf16x8*)&lB[cur][(w * 4 + n) * 512 + hi * 128 + l16 * 8];
            #pragma unroll
            for (int m = 0; m < 4; ++m)
                #pragma unroll
                for (int n = 0; n < 4; ++n)
                    acc2[m][n] = mfma16(a[m], bb[n], acc2[m][n]);
            if ((cc & 7) == 7) {              // flush this half: lane holds 4 consecutive pixels
                int half = cc >> 3;
                #pragma unroll
                for (int n = 0; n < 4; ++n) {
                    int ch = half * 256 + w * 64 + n * 16 + l16;
                    float bc = obias[ch];
                    float* orow = out + ((long)b * 512 + ch) * 16384 + pixg;
                    #pragma unroll
                    for (int m = 0; m < 4; ++m) {
                        float4 v;
                        v.x = fmaxf(acc2[m][n][0] + bc, 0.f);
                        v.y = fmaxf(acc2[m][n][1] + bc, 0.f);
                        v.z = fmaxf(acc2[m][n][2] + bc, 0.f);
                        v.w = fmaxf(acc2[m][n][3] + bc, 0.f);
                        *(float4*)&orow[m * 16 + hi * 4] = v;
                    }
                }
                #pragma unroll
                for (int m = 0; m < 4; ++m)
                    #pragma unroll
                    for (int n = 0; n < 4; ++n)
                        acc2[m][n] = (f32x4){0.f, 0.f, 0.f, 0.f};
            }
            asm volatile("s_waitcnt vmcnt(0)" ::: "memory");   // next chunk DMA done
        }
    }
}

extern "C" void kernel_launch(void* const* d_in, const int* in_sizes, int n_in,
                              void* d_out, int out_size, void* d_ws, size_t ws_size,
                              hipStream_t stream) {
    const float* x    = (const float*)d_in[0];
    const float* prox = (const float*)d_in[1];
    const float* wq1  = (const float*)d_in[2];
    const float* gq1  = (const float*)d_in[3];
    const float* bq1  = (const float*)d_in[4];
    const float* wq2  = (const float*)d_in[5];
    const float* gq2  = (const float*)d_in[6];
    const float* bq2  = (const float*)d_in[7];
    const float* wk1  = (const float*)d_in[8];
    const float* gk1  = (const float*)d_in[9];
    const float* bk1  = (const float*)d_in[10];
    const float* wk2  = (const float*)d_in[11];
    const float* gk2  = (const float*)d_in[12];
    const float* bk2  = (const float*)d_in[13];
    const float* wv   = (const float*)d_in[14];
    const float* gv   = (const float*)d_in[15];
    const float* bv   = (const float*)d_in[16];
    const float* wo   = (const float*)d_in[17];
    const float* go   = (const float*)d_in[18];
    const float* bo   = (const float*)d_in[19];
    float* out = (float*)d_out;

    char* ws = (char*)d_ws;
    u16* Q1   = (u16*)(ws);                      // 64 MB
    u16* KB   = (u16*)(ws + 67108864LL);         // 128 KB
    u16* VB   = KB + 65536;                      // 128 KB
    u16* WQ1B = VB + 65536;
    u16* WQ2B = WQ1B + 131072;
    u16* WOB  = WQ2B + 65536;

    wprep<<<1280, 256, 0, stream>>>(wq1, gq1, wq2, gq2, wo, go, WQ1B, WQ2B, WOB);
    kv_kernel<<<256, 256, 0, stream>>>(prox, wk1, gk1, bk1, wk2, gk2, bk2, wv, gv, bv, KB, VB);
    gemm1_x<<<2048, 256, 0, stream>>>(x, WQ1B, bq1, Q1);
    gemm2_attn_out<<<2048, 256, 0, stream>>>(Q1, WQ2B, bq2, KB, VB, WOB, bo, out);
}

// Round 8
// 245.085 us; speedup vs baseline: 1.3522x; 1.3522x over previous
//
#include <hip/hip_runtime.h>

#define INV_STD 0.9999950000374997f

typedef unsigned short u16;
typedef __bf16 bf16x8 __attribute__((ext_vector_type(8)));
typedef __bf16 bf16x4 __attribute__((ext_vector_type(4)));
typedef float f32x4 __attribute__((ext_vector_type(4)));

__device__ __forceinline__ u16 f2bf(float f) {
    unsigned int u = __float_as_uint(f);
    u += 0x7fffu + ((u >> 16) & 1u);   // RNE
    return (u16)(u >> 16);
}

// async global->LDS, 16B per lane. LDS dest must be wave-uniform base (HW adds lane*16).
__device__ __forceinline__ void gl_lds16(const void* g, void* l) {
    __builtin_amdgcn_global_load_lds(
        (const __attribute__((address_space(1))) unsigned int*)(unsigned long long)g,
        (__attribute__((address_space(3))) unsigned int*)(unsigned int)(unsigned long long)l,
        16, 0, 0);
}

__device__ __forceinline__ f32x4 mfma16(bf16x8 a, bf16x8 b, f32x4 c) {
    return __builtin_amdgcn_mfma_f32_16x16x32_bf16(a, b, c, 0, 0, 0);
}

__device__ __forceinline__ unsigned lds_off(const void* p) {
    return (unsigned)(unsigned long long)p;
}

// hardware transpose read: lane reads 4 bf16 at byte addr +0,+32,+64,+96
__device__ __forceinline__ bf16x4 tr_read(unsigned addr) {
    bf16x4 r;
    asm volatile("ds_read_b64_tr_b16 %0, %1" : "=v"(r) : "v"(addr));
    return r;
}

__device__ __forceinline__ bf16x8 ldg8(const u16* p) {
    return *(const bf16x8*)p;
}

// ---------------- all weight prep in one launch ----------------
__global__ void wprep(const float* __restrict__ wq1, const float* __restrict__ gq1,
                      const float* __restrict__ wq2, const float* __restrict__ gq2,
                      const float* __restrict__ wo,  const float* __restrict__ go,
                      u16* __restrict__ WQ1B, u16* __restrict__ WQ2B, u16* __restrict__ WOB) {
    int blk = blockIdx.x;
    int t = threadIdx.x;
    if (blk < 512) {
        long i = (long)blk * 256 + t;
        int o = (int)(i >> 9);
        int q = (int)(i & 511);
        int r = q & 31;
        int src = (q & ~31) + ((r >> 3) & 3) * 4 + (r & 3) + ((r >> 2) & 1) * 16;
        WQ1B[i] = f2bf(wq1[(long)o * 512 + src] * (INV_STD * gq1[o]));
    } else if (blk < 768) {
        long i = (long)(blk - 512) * 256 + t;
        int o = (int)(i >> 8);
        WQ2B[i] = f2bf(wq2[i] * (INV_STD * gq2[o]));
    } else {
        long i = (long)(blk - 768) * 256 + t;
        int o = (int)(i >> 8);
        WOB[i] = f2bf(wo[i] * (INV_STD * go[o]));
    }
}

// ---------------- k/v path (tiny): one block per (b,p); p in [0,32) with zero-padding ----------------
__global__ __launch_bounds__(256) void kv_kernel(
    const float* __restrict__ proxy,                       // (B,512,19)
    const float* __restrict__ wk1, const float* __restrict__ gk1, const float* __restrict__ bk1,
    const float* __restrict__ wk2, const float* __restrict__ gk2, const float* __restrict__ bk2,
    const float* __restrict__ wv,  const float* __restrict__ gv,  const float* __restrict__ bv,
    u16* __restrict__ KB,                                  // (B,32,256) bf16, rows 19..31 zero
    u16* __restrict__ VB)                                  // (B,256,32) bf16, cols 19..31 zero
{
    int b = blockIdx.x >> 5, p = blockIdx.x & 31;
    int t = threadIdx.x;
    if (p >= 19) {
        KB[((long)b * 32 + p) * 256 + t] = 0;
        VB[((long)b * 256 + t) * 32 + p] = 0;
        return;
    }
    __shared__ float px[512];
    __shared__ float k1[256];
    for (int i = t; i < 512; i += 256) px[i] = proxy[((long)b * 512 + i) * 19 + p];
    __syncthreads();
    float aK = 0.f, aV = 0.f;
    const float4* wk1r = (const float4*)(wk1 + (long)t * 512);
    const float4* wvr  = (const float4*)(wv  + (long)t * 512);
    const float4* pxv  = (const float4*)px;
    #pragma unroll 4
    for (int c = 0; c < 128; ++c) {
        float4 pv = pxv[c];
        float4 k4 = wk1r[c];
        float4 v4 = wvr[c];
        aK += k4.x * pv.x + k4.y * pv.y + k4.z * pv.z + k4.w * pv.w;
        aV += v4.x * pv.x + v4.y * pv.y + v4.z * pv.z + v4.w * pv.w;
    }
    float k1v = fmaxf(aK * (INV_STD * gk1[t]) + bk1[t], 0.f);
    float vv  = fmaxf(aV * (INV_STD * gv[t])  + bv[t],  0.f);
    k1[t] = k1v;
    VB[((long)b * 256 + t) * 32 + p] = f2bf(vv);
    __syncthreads();
    float a2 = 0.f;
    const float4* wk2r = (const float4*)(wk2 + (long)t * 256);
    const float4* k1v4 = (const float4*)k1;
    #pragma unroll 4
    for (int c = 0; c < 64; ++c) {
        float4 w4 = wk2r[c];
        float4 kk = k1v4[c];
        a2 += w4.x * kk.x + w4.y * kk.y + w4.z * kk.z + w4.w * kk.w;
    }
    KB[((long)b * 32 + p) * 256 + t] = f2bf(fmaxf(a2 * (INV_STD * gk2[t]) + bk2[t], 0.f));
}

// ---------------- fully fused: gemm1 -> gemm2 -> attention -> output projection ----------------
// Per 64-pixel block, 4 waves. q1/q2/ctx live in one 33 KB LDS buffer (sequential reuse).
__global__ __launch_bounds__(256, 2) void fused_all(
    const float* __restrict__ X,     // (B,512,16384) f32
    const u16* __restrict__ W1,      // (256,512) bf16, K-permuted
    const float* __restrict__ b1,
    const u16* __restrict__ W2,      // (256,256) bf16
    const float* __restrict__ b2,
    const u16* __restrict__ KB,      // (B,32,256) bf16
    const u16* __restrict__ VB,      // (B,256,32) bf16
    const u16* __restrict__ Wo,      // (512,256) bf16
    const float* __restrict__ obias,
    float* __restrict__ out)         // (B,512,16384) f32
{
    __shared__ __align__(16) u16 xs[64 * 64];      //  8 KB, tr-subtiled x tile
    __shared__ __align__(16) u16 lB[2][256 * 32];  // 32 KB, W2/Wo staging (dbuf)
    __shared__ __align__(16) u16 q12s[64 * 264];   // 33 KB: q1 -> q2 -> ctx
    __shared__ __align__(16) u16 atts[64 * 40];    //  5 KB
    int t = threadIdx.x, lane = t & 63, w = t >> 6;
    int l16 = lane & 15, hi = lane >> 4;
    long m0 = (long)blockIdx.x * 64;
    int b = (int)(m0 >> 14);
    int pixg = (int)(m0 & 16383);
    const float* xb = X + (long)b * 512 * 16384 + pixg;
    int ca = t >> 4;       // channel within 16-group
    int aa = t & 15;       // pixel quad
    int rW = lane >> 2;            // staging row within 16-row group
    int cW = (lane & 3) << 3;      // staging col (u16)
    unsigned trb = lds_off(&xs[hi * 64 + l16]);

    // ================= phase A: gemm1, q1 = relu(x^T · W1^T + b1) =================
    {
        f32x4 acc[4][4] = {};
        float4 xr0, xr1, xr2, xr3;
        {
            const float* p0 = xb + (long)ca * 16384 + aa * 4;
            xr0 = *(const float4*)(p0);
            xr1 = *(const float4*)(p0 + 16L * 16384);
            xr2 = *(const float4*)(p0 + 32L * 16384);
            xr3 = *(const float4*)(p0 + 48L * 16384);
        }
        #define STW(XR, P) { \
            int c = (P) * 16 + ca; \
            ushort4 u; u.x = f2bf(XR.x); u.y = f2bf(XR.y); u.z = f2bf(XR.z); u.w = f2bf(XR.w); \
            *(ushort4*)&xs[((aa >> 2) * 16 + (c >> 2)) * 64 + (c & 3) * 16 + (aa & 3) * 4] = u; }
        for (int kt = 0; kt < 8; ++kt) {
            int k0 = kt << 6;
            if (kt > 0) __syncthreads();         // xs free (prev kt's tr_reads done)
            STW(xr0, 0) STW(xr1, 1) STW(xr2, 2) STW(xr3, 3)
            __syncthreads();                     // xs ready
            // W frags first (L2) so their vmcnt wait doesn't chain on the HBM x-prefetch
            bf16x8 bb0[4], bb1[4];
            #pragma unroll
            for (int j = 0; j < 4; ++j) {
                const u16* wr = W1 + (long)(w * 64 + j * 16 + l16) * 512 + k0 + hi * 8;
                bb0[j] = ldg8(wr);
                bb1[j] = ldg8(wr + 32);
            }
            if (kt < 7) {                        // HBM prefetch for next tile
                const float* p0 = xb + (long)(k0 + 64 + ca) * 16384 + aa * 4;
                xr0 = *(const float4*)(p0);
                xr1 = *(const float4*)(p0 + 16L * 16384);
                xr2 = *(const float4*)(p0 + 32L * 16384);
                xr3 = *(const float4*)(p0 + 48L * 16384);
            }
            bf16x4 lo0[4], hh0[4], lo1[4], hh1[4];
            #pragma unroll
            for (int i = 0; i < 4; ++i) {
                unsigned a0 = trb + i * 2048;
                lo0[i] = tr_read(a0);
                hh0[i] = tr_read(a0 + 512);
            }
            #pragma unroll
            for (int i = 0; i < 4; ++i) {
                unsigned a0 = trb + i * 2048 + 1024;
                lo1[i] = tr_read(a0);
                hh1[i] = tr_read(a0 + 512);
            }
            asm volatile("s_waitcnt lgkmcnt(8)" ::: "memory");
            __builtin_amdgcn_sched_barrier(0);
            #pragma unroll
            for (int i = 0; i < 4; ++i) {
                bf16x8 a = __builtin_shufflevector(lo0[i], hh0[i], 0, 1, 2, 3, 4, 5, 6, 7);
                #pragma unroll
                for (int j = 0; j < 4; ++j)
                    acc[i][j] = mfma16(a, bb0[j], acc[i][j]);
            }
            asm volatile("s_waitcnt lgkmcnt(0)" ::: "memory");
            __builtin_amdgcn_sched_barrier(0);
            #pragma unroll
            for (int i = 0; i < 4; ++i) {
                bf16x8 a = __builtin_shufflevector(lo1[i], hh1[i], 0, 1, 2, 3, 4, 5, 6, 7);
                #pragma unroll
                for (int j = 0; j < 4; ++j)
                    acc[i][j] = mfma16(a, bb1[j], acc[i][j]);
            }
        }
        #undef STW
        // epilogue: q1 -> q12s (bf16), and prefetch W2 chunk 0 into lB[0]
        #pragma unroll
        for (int j = 0; j < 4; ++j) {
            int q = w * 4 + j;
            gl_lds16(W2 + (long)(q * 16 + rW) * 256 + cW, &lB[0][q * 512]);
        }
        float bj[4];
        #pragma unroll
        for (int j = 0; j < 4; ++j) bj[j] = b1[w * 64 + j * 16 + l16];
        #pragma unroll
        for (int i = 0; i < 4; ++i)
            #pragma unroll
            for (int r = 0; r < 4; ++r) {
                int pix = i * 16 + hi * 4 + r;
                #pragma unroll
                for (int j = 0; j < 4; ++j) {
                    float v = acc[i][j][r] + bj[j];
                    q12s[pix * 264 + w * 64 + j * 16 + l16] = f2bf(fmaxf(v, 0.f));
                }
            }
    }
    __syncthreads();       // q1 visible + W2 chunk0 staged
    // ================= phase B: gemm2, q2 = relu(q1 · W2^T + b2), A from q12s =================
    {
        f32x4 acc[4][4] = {};
        #pragma unroll
        for (int c = 0; c < 8; ++c) {
            int cur = c & 1;
            if (c < 7) {                         // stage next W2 chunk
                int k1 = (c + 1) << 5;
                #pragma unroll
                for (int j = 0; j < 4; ++j) {
                    int q = w * 4 + j;
                    gl_lds16(W2 + (long)(q * 16 + rW) * 256 + k1 + cW, &lB[cur ^ 1][q * 512]);
                }
            }
            bf16x8 a[4], bb[4];
            #pragma unroll
            for (int i = 0; i < 4; ++i)
                a[i] = *(const bf16x8*)&q12s[(i * 16 + l16) * 264 + (c << 5) + hi * 8];
            #pragma unroll
            for (int j = 0; j < 4; ++j)
                bb[j] = *(const bf16x8*)&lB[cur][(w * 64 + j * 16 + l16) * 32 + hi * 8];
            #pragma unroll
            for (int i = 0; i < 4; ++i)
                #pragma unroll
                for (int j = 0; j < 4; ++j)
                    acc[i][j] = mfma16(a[i], bb[j], acc[i][j]);
            __syncthreads();                     // drains next-chunk DMA (overlapped) + fences q12s
        }
        // epilogue: q2 -> q12s (all q1 reads complete after last sync)
        float bj[4];
        #pragma unroll
        for (int j = 0; j < 4; ++j) bj[j] = b2[w * 64 + j * 16 + l16];
        #pragma unroll
        for (int i = 0; i < 4; ++i)
            #pragma unroll
            for (int r = 0; r < 4; ++r) {
                int pix = i * 16 + hi * 4 + r;
                #pragma unroll
                for (int j = 0; j < 4; ++j) {
                    float v = acc[i][j][r] + bj[j];
                    q12s[pix * 264 + w * 64 + j * 16 + l16] = f2bf(fmaxf(v, 0.f));
                }
            }
    }
    __syncthreads();
    // ================= phase C: sim = q2 · KB^T, softmax -> atts =================
    {
        f32x4 s0 = {}, s1 = {};
        #pragma unroll
        for (int ks = 0; ks < 8; ++ks) {
            bf16x8 a = *(const bf16x8*)&q12s[(w * 16 + l16) * 264 + ks * 32 + hi * 8];
            bf16x8 b0 = ldg8(KB + ((long)b * 32 + l16) * 256 + ks * 32 + hi * 8);
            bf16x8 b1v = ldg8(KB + ((long)b * 32 + 16 + l16) * 256 + ks * 32 + hi * 8);
            s0 = mfma16(a, b0, s0);
            s1 = mfma16(a, b1v, s1);
        }
        const float scale = 0.0625f;
        #pragma unroll
        for (int r = 0; r < 4; ++r) {
            float v0 = s0[r] * scale;
            float v1 = s1[r] * scale;
            float mx = fmaxf(v0, v1);
            mx = fmaxf(mx, __shfl_xor(mx, 1));
            mx = fmaxf(mx, __shfl_xor(mx, 2));
            mx = fmaxf(mx, __shfl_xor(mx, 4));
            mx = fmaxf(mx, __shfl_xor(mx, 8));
            float e0 = __expf(v0 - mx);
            float e1 = (l16 < 3) ? __expf(v1 - mx) : 0.f;
            float s = e0 + e1;
            s += __shfl_xor(s, 1);
            s += __shfl_xor(s, 2);
            s += __shfl_xor(s, 4);
            s += __shfl_xor(s, 8);
            float inv = 1.f / s;
            int pix = w * 16 + hi * 4 + r;
            atts[pix * 40 + l16] = f2bf(e0 * inv);
            atts[pix * 40 + 16 + l16] = (l16 < 3) ? f2bf(e1 * inv) : (u16)0;
        }
    }
    __syncthreads();       // sim reads of q12s complete; q12s reusable as ctx
    // ================= phase D: ctx = att · VB^T -> q12s =================
    {
        f32x4 c4[4][4] = {};
        bf16x8 av[4], bv[4];
        #pragma unroll
        for (int mf = 0; mf < 4; ++mf)
            av[mf] = *(const bf16x8*)&atts[(mf * 16 + l16) * 40 + hi * 8];
        #pragma unroll
        for (int nf = 0; nf < 4; ++nf)
            bv[nf] = ldg8(VB + ((long)b * 256 + w * 64 + nf * 16 + l16) * 32 + hi * 8);
        #pragma unroll
        for (int mf = 0; mf < 4; ++mf)
            #pragma unroll
            for (int nf = 0; nf < 4; ++nf)
                c4[mf][nf] = mfma16(av[mf], bv[nf], c4[mf][nf]);
        #pragma unroll
        for (int mf = 0; mf < 4; ++mf)
            #pragma unroll
            for (int r = 0; r < 4; ++r) {
                int pix = mf * 16 + hi * 4 + r;
                #pragma unroll
                for (int nf = 0; nf < 4; ++nf)
                    q12s[pix * 264 + w * 64 + nf * 16 + l16] = f2bf(c4[mf][nf][r]);
            }
        // prefetch Wo chunk 0 (lB idle since phase B)
        #pragma unroll
        for (int j = 0; j < 4; ++j) {
            int q = w * 4 + j;
            gl_lds16(Wo + (long)(q * 16 + rW) * 256 + cW, &lB[0][q * 512]);
        }
    }
    __syncthreads();       // ctx visible + Wo chunk0 staged
    // ================= phase E: out = relu(Wo · ctx^T + bo), operand-swapped, float4 stores =================
    {
        f32x4 acc2[4][4] = {};
        #pragma unroll
        for (int cc = 0; cc < 16; ++cc) {
            int cur = cc & 1;
            if (cc < 15) {
                int nc = cc + 1;
                #pragma unroll
                for (int j = 0; j < 4; ++j) {
                    int q = w * 4 + j;
                    gl_lds16(Wo + (long)((nc >> 3) * 256 + q * 16 + rW) * 256 + ((nc & 7) << 5) + cW,
                             &lB[cur ^ 1][q * 512]);
                }
            }
            int k0 = (cc & 7) << 5;
            bf16x8 a[4], bb[4];
            #pragma unroll
            for (int m = 0; m < 4; ++m)       // ctx rows (pixels = M)
                a[m] = *(const bf16x8*)&q12s[(m * 16 + l16) * 264 + k0 + hi * 8];
            #pragma unroll
            for (int n = 0; n < 4; ++n)       // Wo rows (channels = N)
                bb[n] = *(const bf16x8*)&lB[cur][(w * 64 + n * 16 + l16) * 32 + hi * 8];
            #pragma unroll
            for (int m = 0; m < 4; ++m)
                #pragma unroll
                for (int n = 0; n < 4; ++n)
                    acc2[m][n] = mfma16(a[m], bb[n], acc2[m][n]);
            if ((cc & 7) == 7) {              // flush this half: lane holds 4 consecutive pixels
                int half = cc >> 3;
                #pragma unroll
                for (int n = 0; n < 4; ++n) {
                    int ch = half * 256 + w * 64 + n * 16 + l16;
                    float bc = obias[ch];
                    float* orow = out + ((long)b * 512 + ch) * 16384 + pixg;
                    #pragma unroll
                    for (int m = 0; m < 4; ++m) {
                        float4 v;
                        v.x = fmaxf(acc2[m][n][0] + bc, 0.f);
                        v.y = fmaxf(acc2[m][n][1] + bc, 0.f);
                        v.z = fmaxf(acc2[m][n][2] + bc, 0.f);
                        v.w = fmaxf(acc2[m][n][3] + bc, 0.f);
                        *(float4*)&orow[m * 16 + hi * 4] = v;
                    }
                }
                #pragma unroll
                for (int m = 0; m < 4; ++m)
                    #pragma unroll
                    for (int n = 0; n < 4; ++n)
                        acc2[m][n] = (f32x4){0.f, 0.f, 0.f, 0.f};
            }
            __syncthreads();
        }
    }
}

extern "C" void kernel_launch(void* const* d_in, const int* in_sizes, int n_in,
                              void* d_out, int out_size, void* d_ws, size_t ws_size,
                              hipStream_t stream) {
    const float* x    = (const float*)d_in[0];
    const float* prox = (const float*)d_in[1];
    const float* wq1  = (const float*)d_in[2];
    const float* gq1  = (const float*)d_in[3];
    const float* bq1  = (const float*)d_in[4];
    const float* wq2  = (const float*)d_in[5];
    const float* gq2  = (const float*)d_in[6];
    const float* bq2  = (const float*)d_in[7];
    const float* wk1  = (const float*)d_in[8];
    const float* gk1  = (const float*)d_in[9];
    const float* bk1  = (const float*)d_in[10];
    const float* wk2  = (const float*)d_in[11];
    const float* gk2  = (const float*)d_in[12];
    const float* bk2  = (const float*)d_in[13];
    const float* wv   = (const float*)d_in[14];
    const float* gv   = (const float*)d_in[15];
    const float* bv   = (const float*)d_in[16];
    const float* wo   = (const float*)d_in[17];
    const float* go   = (const float*)d_in[18];
    const float* bo   = (const float*)d_in[19];
    float* out = (float*)d_out;

    char* ws = (char*)d_ws;
    u16* KB   = (u16*)(ws);                      // 128 KB
    u16* VB   = KB + 65536;                      // 128 KB
    u16* WQ1B = VB + 65536;                      // 256 KB
    u16* WQ2B = WQ1B + 131072;                   // 128 KB
    u16* WOB  = WQ2B + 65536;                    // 256 KB

    wprep<<<1280, 256, 0, stream>>>(wq1, gq1, wq2, gq2, wo, go, WQ1B, WQ2B, WOB);
    kv_kernel<<<256, 256, 0, stream>>>(prox, wk1, gk1, bk1, wk2, gk2, bk2, wv, gv, bv, KB, VB);
    fused_all<<<2048, 256, 0, stream>>>(x, WQ1B, bq1, WQ2B, bq2, KB, VB, WOB, bo, out);
}